// Round 1
// baseline (980.516 us; speedup 1.0000x reference)
//
#include <hip/hip_runtime.h>
#include <hip/hip_bf16.h>
#include <math.h>

// Problem constants (fixed by reference):
//   patches B = 512 (= b16 * D2 * H4 * W4), tokens P = 8, channels C = 128, HEADS = 8
//   attn per (patch, head): Q^T K over p (K-dim 8) -> 128x128, instance-norm over whole map,
//   softmax over axis j, ctx = attn @ V^T -> 128x8, rearrange, @ Wout (1024x128).

#define C     128
#define PP    8
#define HEADS 8
#define ATT_LD 129   // pad 128-stride to 129 words: (i*129+j)%32 = (i+j)%32 -> conflict-free

__global__ __launch_bounds__(256) void attn_fused_kernel(
    const float* __restrict__ emb,   // (512, 8, 128)
    const float* __restrict__ Wq,    // (128, 1024)  col = ci*8 + h
    const float* __restrict__ Wk,
    const float* __restrict__ Wv,
    float* __restrict__ ctx_ws)      // (4096, 1024) in OUTPUT row order, col = ci*8 + h
{
    const int blk = blockIdx.x;      // 0..4095
    const int bp  = blk >> 3;       // patch 0..511
    const int h   = blk & 7;        // head 0..7
    const int t   = threadIdx.x;    // 0..255

    __shared__ float emb_s[PP * C];            // 4 KB
    __shared__ float Qs[PP * C];               // 4 KB   Q[p][i]
    __shared__ float Ks[PP * C];               // 4 KB
    __shared__ float Vs[PP * C];               // 4 KB
    __shared__ float attn_s[C * ATT_LD];       // 66 KB
    __shared__ float red_max[C * 2];
    __shared__ float red_sum[C * 2];
    __shared__ float bredS[4], bredQ[4];
    __shared__ float stat[2];                  // mu, rsigma

    // ---- 1. load emb[bp] (8x128 = 1024 floats) ----
    {
        const float4* src = (const float4*)(emb + (size_t)bp * PP * C);
        ((float4*)emb_s)[t] = src[t];          // 256 * float4
    }
    __syncthreads();

    // ---- 2. QKV projections: X[p][i] = emb_s[p][:] . W[:, i*8+h] ----
    {
        const int i  = t & 127;
        const int pp = t >> 7;                 // 0/1 -> rows {pp, pp+2, pp+4, pp+6}
        const int col = i * HEADS + h;
        float aq[4] = {0,0,0,0}, ak[4] = {0,0,0,0}, av[4] = {0,0,0,0};
        for (int k0 = 0; k0 < C; ++k0) {
            const float wq = Wq[k0 * (C * HEADS) + col];
            const float wk = Wk[k0 * (C * HEADS) + col];
            const float wv = Wv[k0 * (C * HEADS) + col];
            #pragma unroll
            for (int r = 0; r < 4; ++r) {
                const float e = emb_s[(pp + 2 * r) * C + k0];   // broadcast read
                aq[r] += e * wq;
                ak[r] += e * wk;
                av[r] += e * wv;
            }
        }
        #pragma unroll
        for (int r = 0; r < 4; ++r) {
            Qs[(pp + 2 * r) * C + i] = aq[r];
            Ks[(pp + 2 * r) * C + i] = ak[r];
            Vs[(pp + 2 * r) * C + i] = av[r];
        }
    }
    __syncthreads();

    // ---- 3. attn[i][j] = sum_p Q[p][i]*K[p][j], accumulate sum/sumsq ----
    {
        const int j  = t & 127;
        const int i0 = t >> 7;
        float kk[PP];
        #pragma unroll
        for (int p = 0; p < PP; ++p) kk[p] = Ks[p * C + j];
        float lsum = 0.f, lsq = 0.f;
        for (int m = 0; m < 64; ++m) {
            const int i = i0 + 2 * m;
            float a = 0.f;
            #pragma unroll
            for (int p = 0; p < PP; ++p) a += Qs[p * C + i] * kk[p];
            attn_s[i * ATT_LD + j] = a;
            lsum += a;
            lsq  += a * a;
        }
        // block reduction for mean / var (64-lane wave reduce, then 4 waves)
        #pragma unroll
        for (int off = 32; off > 0; off >>= 1) {
            lsum += __shfl_down(lsum, off);
            lsq  += __shfl_down(lsq,  off);
        }
        const int lane = t & 63, wid = t >> 6;
        if (lane == 0) { bredS[wid] = lsum; bredQ[wid] = lsq; }
    }
    __syncthreads();
    if (t == 0) {
        const float s = bredS[0] + bredS[1] + bredS[2] + bredS[3];
        const float q = bredQ[0] + bredQ[1] + bredQ[2] + bredQ[3];
        const float mu  = s * (1.0f / (128.0f * 128.0f));
        const float var = q * (1.0f / (128.0f * 128.0f)) - mu * mu;
        stat[0] = mu;
        stat[1] = rsqrtf(var + 1e-5f);
    }
    __syncthreads();

    // ---- 4. instance-norm + row softmax (two threads per row) ----
    {
        const int r    = t & 127;
        const int half = t >> 7;
        const float mu = stat[0], rs = stat[1];
        const int base = r * ATT_LD + half * 64;
        float mx = -3.4e38f;
        for (int jj = 0; jj < 64; ++jj) {
            const float a = (attn_s[base + jj] - mu) * rs;
            attn_s[base + jj] = a;
            mx = fmaxf(mx, a);
        }
        red_max[r * 2 + half] = mx;
        __syncthreads();
        const float m = fmaxf(red_max[r * 2 + 0], red_max[r * 2 + 1]);
        float ssum = 0.f;
        for (int jj = 0; jj < 64; ++jj) {
            const float e = __expf(attn_s[base + jj] - m);
            attn_s[base + jj] = e;
            ssum += e;
        }
        red_sum[r * 2 + half] = ssum;
    }
    __syncthreads();

    // ---- 5. ctx[i][p] = inv_s[i] * sum_j e[i][j] * V[p][j]; store rearranged ----
    {
        const int i  = t & 127;
        const int pp = t >> 7;
        const float inv = 1.0f / (red_sum[i * 2 + 0] + red_sum[i * 2 + 1]);
        float acc[4] = {0,0,0,0};
        for (int j = 0; j < C; ++j) {
            const float e = attn_s[i * ATT_LD + j];    // conflict-free (stride 129)
            #pragma unroll
            for (int r = 0; r < 4; ++r)
                acc[r] += e * Vs[(pp + 2 * r) * C + j]; // broadcast read
        }
        // output-row mapping:
        //   bp = ((b*2 + d)*4 + h_)*4 + w ; p = p1*4 + p2*2 + p3
        //   tok = ((((d*2+p1)*4 + h_)*2 + p2)*4 + w)*2 + p3 ; row = b*256 + tok
        const int b   = bp >> 5;
        const int rem = bp & 31;
        const int d   = rem >> 4;
        const int h_  = (rem >> 2) & 3;
        const int w   = rem & 3;
        #pragma unroll
        for (int r = 0; r < 4; ++r) {
            const int p  = pp + 2 * r;
            const int p1 = p >> 2, p2 = (p >> 1) & 1, p3 = p & 1;
            const int tok = ((((d * 2 + p1) * 4 + h_) * 2 + p2) * 4 + w) * 2 + p3;
            const int row = b * 256 + tok;
            ctx_ws[(size_t)row * (C * HEADS) + i * HEADS + h] = acc[r] * inv;
        }
    }
}

// out (4096,128) = ctx_ws (4096,1024) @ Wout (1024,128), plain fp32 tiled GEMM.
__global__ __launch_bounds__(256) void out_gemm_kernel(
    const float* __restrict__ ctx,   // (4096, 1024)
    const float* __restrict__ Wout,  // (1024, 128)
    float* __restrict__ out)         // (4096, 128)
{
    __shared__ float ctx_s[16 * 128];            // 8 KB tile: 16 rows x 128 k
    const int t    = threadIdx.x;
    const int col  = t & 127;
    const int rg   = t >> 7;                     // 0/1 -> 8 rows each
    const int row0 = blockIdx.x * 16;

    float acc[8] = {0,0,0,0,0,0,0,0};
    for (int kb = 0; kb < 8; ++kb) {
        __syncthreads();
        // stage 16x128 chunk: 512 float4, 2 per thread
        #pragma unroll
        for (int u = 0; u < 2; ++u) {
            const int f  = t * 2 + u;
            const int r  = f >> 5;
            const int k4 = f & 31;
            ((float4*)ctx_s)[r * 32 + k4] =
                *(const float4*)&ctx[(size_t)(row0 + r) * 1024 + kb * 128 + k4 * 4];
        }
        __syncthreads();
        for (int k4 = 0; k4 < 32; ++k4) {
            const int kbase = kb * 128 + k4 * 4;
            const float w0 = Wout[(kbase + 0) * 128 + col];
            const float w1 = Wout[(kbase + 1) * 128 + col];
            const float w2 = Wout[(kbase + 2) * 128 + col];
            const float w3 = Wout[(kbase + 3) * 128 + col];
            #pragma unroll
            for (int r = 0; r < 8; ++r) {
                const float4 cv = ((const float4*)ctx_s)[(rg * 8 + r) * 32 + k4];
                acc[r] += cv.x * w0 + cv.y * w1 + cv.z * w2 + cv.w * w3;
            }
        }
    }
    #pragma unroll
    for (int r = 0; r < 8; ++r)
        out[(size_t)(row0 + rg * 8 + r) * 128 + col] = acc[r];
}

extern "C" void kernel_launch(void* const* d_in, const int* in_sizes, int n_in,
                              void* d_out, int out_size, void* d_ws, size_t ws_size,
                              hipStream_t stream) {
    const float* emb  = (const float*)d_in[0];   // (512, 8, 128)
    const float* Wq   = (const float*)d_in[1];   // (128, 1024)
    const float* Wk   = (const float*)d_in[2];
    const float* Wv   = (const float*)d_in[3];
    const float* Wout = (const float*)d_in[4];   // (1024, 128)
    float* out    = (float*)d_out;               // (16, 256, 128) = 524288 floats
    float* ctx_ws = (float*)d_ws;                // needs 4096*1024*4 = 16 MB

    attn_fused_kernel<<<4096, 256, 0, stream>>>(emb, Wq, Wk, Wv, ctx_ws);
    out_gemm_kernel<<<256, 256, 0, stream>>>(ctx_ws, Wout, out);
}

// Round 2
// 253.275 us; speedup vs baseline: 3.8713x; 3.8713x over previous
//
#include <hip/hip_runtime.h>
#include <hip/hip_bf16.h>
#include <math.h>

// Self_Attention_Local: 512 patches x 8 heads; per (patch,head):
//   QKV proj (8x128 @ 128x128), scores 128x128 (K=8), instance-norm over map,
//   row softmax, PV (128x128 @ 128x8... as 128x8 ctx), rearrange, @ Wout.
//
// R2 design: score tile register-resident (4x16 per thread), shfl_xor butterfly
// reductions, LDS only for emb/Q/K/V (16.5 KB -> ~3 blocks/CU vs 1 before),
// h-major ctx workspace (coalesced writes, kills 8x write amplification),
// pre-permuted W [h][k][i] for coalesced weight reads (ws_size-guarded).

#define C     128
#define PP    8
#define HEADS 8

// ---- Kernel A: permute Wq/Wk/Wv from [k][i*8+h] to [h][k][i] ----
__global__ __launch_bounds__(256) void permute_w_kernel(
    const float* __restrict__ Wq, const float* __restrict__ Wk,
    const float* __restrict__ Wv, float* __restrict__ Wp)
{
    const int gid = blockIdx.x * 256 + threadIdx.x;   // 0..131071, source-major
    const int k = gid >> 10;        // source row
    const int c = gid & 1023;       // source col = i*8 + h
    const int h = c & 7;
    const int i = c >> 3;
    const int dst = h * 16384 + k * 128 + i;
    Wp[dst]          = Wq[gid];
    Wp[131072 + dst] = Wk[gid];
    Wp[262144 + dst] = Wv[gid];
}

// ---- Kernel B: fused attention, one block per (patch, head) ----
__global__ __launch_bounds__(256) void attn_fused2(
    const float* __restrict__ emb,   // (512, 8, 128)
    const float* __restrict__ Wq_,   // perm ? [h][k][i] : [k][i*8+h]
    const float* __restrict__ Wk_,
    const float* __restrict__ Wv_,
    const int perm,
    float* __restrict__ ctx2)        // [h][4096 out-order rows][128]
{
    const int blk = blockIdx.x;      // 0..4095
    const int bp  = blk >> 3;        // patch
    const int h   = blk & 7;         // head
    const int t   = threadIdx.x;     // 0..255

    __shared__ float emb_s[PP * C];  // 4 KB, reused as ctx staging at the end
    __shared__ float Qs[PP * C];     // Q[p][i]
    __shared__ float Ks[PP * C];
    __shared__ float Vs[PP * C];
    __shared__ float redA[4], redB[4];
    __shared__ float stat[2];

    // 1. load emb[bp] (1024 floats)
    ((float4*)emb_s)[t] = ((const float4*)(emb + (size_t)bp * PP * C))[t];
    __syncthreads();

    // 2. QKV projections: X[p][i] = emb[p][:] . Wx[:, i*8+h]
    {
        const int i  = t & 127;
        const int pp = t >> 7;                  // rows {pp, pp+2, pp+4, pp+6}
        const int wofs = perm ? (h * 16384 + i) : (i * 8 + h);
        const int wstr = perm ? 128 : 1024;
        float aq[4] = {0,0,0,0}, ak[4] = {0,0,0,0}, av[4] = {0,0,0,0};
        const float4* e4 = (const float4*)emb_s;
        for (int k4 = 0; k4 < 32; ++k4) {
            float ea[4][4];
            #pragma unroll
            for (int r = 0; r < 4; ++r) {
                const float4 x = e4[(pp + 2*r) * 32 + k4];  // broadcast read
                ea[r][0] = x.x; ea[r][1] = x.y; ea[r][2] = x.z; ea[r][3] = x.w;
            }
            #pragma unroll
            for (int u = 0; u < 4; ++u) {
                const int k = k4 * 4 + u;
                const float wq = Wq_[k * wstr + wofs];      // coalesced when perm
                const float wk = Wk_[k * wstr + wofs];
                const float wv = Wv_[k * wstr + wofs];
                #pragma unroll
                for (int r = 0; r < 4; ++r) {
                    aq[r] = fmaf(ea[r][u], wq, aq[r]);
                    ak[r] = fmaf(ea[r][u], wk, ak[r]);
                    av[r] = fmaf(ea[r][u], wv, av[r]);
                }
            }
        }
        #pragma unroll
        for (int r = 0; r < 4; ++r) {
            Qs[(pp + 2*r) * C + i] = aq[r];
            Ks[(pp + 2*r) * C + i] = ak[r];
            Vs[(pp + 2*r) * C + i] = av[r];
        }
    }
    __syncthreads();

    // Thread tile: 4 rows (i) x 16 cols (j) of the 128x128 score map.
    // rg = t>>3 (32 row groups), cg = t&7 (8 col groups; consecutive lanes ->
    // col-group reductions are shfl_xor offsets 1,2,4 within a wave).
    const int rg = t >> 3;
    const int cg = t & 7;

    float S[4][16];
    #pragma unroll
    for (int rr = 0; rr < 4; ++rr)
        #pragma unroll
        for (int jj = 0; jj < 16; ++jj) S[rr][jj] = 0.0f;

    // 3. scores S[i][j] = sum_p Q[p][i] K[p][j]
    {
        const float4* Qs4 = (const float4*)Qs;
        const float4* Ks4 = (const float4*)Ks;
        #pragma unroll
        for (int p = 0; p < 8; ++p) {
            const float4 qv = Qs4[p*32 + rg];             // conflict-free
            float q[4] = {qv.x, qv.y, qv.z, qv.w};
            float kk[16];
            #pragma unroll
            for (int u = 0; u < 4; ++u) {
                const float4 kv = Ks4[p*32 + cg*4 + u];   // 4-way conflict, ok
                kk[u*4+0] = kv.x; kk[u*4+1] = kv.y; kk[u*4+2] = kv.z; kk[u*4+3] = kv.w;
            }
            #pragma unroll
            for (int rr = 0; rr < 4; ++rr)
                #pragma unroll
                for (int jj = 0; jj < 16; ++jj)
                    S[rr][jj] = fmaf(q[rr], kk[jj], S[rr][jj]);
        }
    }

    // 4a. instance-norm stats over the whole 128x128 map
    {
        float ls = 0.f, lq = 0.f;
        #pragma unroll
        for (int rr = 0; rr < 4; ++rr)
            #pragma unroll
            for (int jj = 0; jj < 16; ++jj) {
                ls += S[rr][jj];
                lq = fmaf(S[rr][jj], S[rr][jj], lq);
            }
        #pragma unroll
        for (int off = 32; off >= 1; off >>= 1) {
            ls += __shfl_xor(ls, off);
            lq += __shfl_xor(lq, off);
        }
        if ((t & 63) == 0) { redA[t >> 6] = ls; redB[t >> 6] = lq; }
    }
    __syncthreads();
    if (t == 0) {
        const float s = redA[0] + redA[1] + redA[2] + redA[3];
        const float q = redB[0] + redB[1] + redB[2] + redB[3];
        const float mu  = s * (1.0f / 16384.0f);
        const float var = q * (1.0f / 16384.0f) - mu * mu;
        stat[0] = mu;
        stat[1] = rsqrtf(var + 1e-5f);
    }
    __syncthreads();
    const float rs = stat[1];

    // 4b. softmax per row: exp((S - rowmax_raw)*rs) — algebra folds the norm:
    //     (S-mu)*rs - (max-mu)*rs == (S-max)*rs
    float inv[4];
    #pragma unroll
    for (int rr = 0; rr < 4; ++rr) {
        float m = S[rr][0];
        #pragma unroll
        for (int jj = 1; jj < 16; ++jj) m = fmaxf(m, S[rr][jj]);
        #pragma unroll
        for (int off = 1; off <= 4; off <<= 1) m = fmaxf(m, __shfl_xor(m, off));
        float sum = 0.f;
        #pragma unroll
        for (int jj = 0; jj < 16; ++jj) {
            const float e = __expf((S[rr][jj] - m) * rs);
            S[rr][jj] = e;
            sum += e;
        }
        #pragma unroll
        for (int off = 1; off <= 4; off <<= 1) sum += __shfl_xor(sum, off);
        inv[rr] = 1.0f / sum;
    }

    // 5. PV: ctx[i][p] = inv[i] * sum_j e[i][j] V[p][j]; reduce over col groups
    {
        const float4* Vs4 = (const float4*)Vs;
        float acc[4][8];
        #pragma unroll
        for (int p = 0; p < 8; ++p) {
            float vv[16];
            #pragma unroll
            for (int u = 0; u < 4; ++u) {
                const float4 x = Vs4[p*32 + cg*4 + u];
                vv[u*4+0] = x.x; vv[u*4+1] = x.y; vv[u*4+2] = x.z; vv[u*4+3] = x.w;
            }
            #pragma unroll
            for (int rr = 0; rr < 4; ++rr) {
                float a = 0.f;
                #pragma unroll
                for (int jj = 0; jj < 16; ++jj)
                    a = fmaf(S[rr][jj], vv[jj], a);
                acc[rr][p] = a;
            }
        }
        #pragma unroll
        for (int off = 1; off <= 4; off <<= 1)
            #pragma unroll
            for (int rr = 0; rr < 4; ++rr)
                #pragma unroll
                for (int p = 0; p < 8; ++p)
                    acc[rr][p] += __shfl_xor(acc[rr][p], off);
        if (cg == 0) {
            float* ctx_s = emb_s;   // emb dead; reuse as ctx staging [p][i]
            #pragma unroll
            for (int p = 0; p < 8; ++p)
                #pragma unroll
                for (int rr = 0; rr < 4; ++rr)
                    ctx_s[p * C + rg * 4 + rr] = acc[rr][p] * inv[rr];
        }
    }
    __syncthreads();

    // 6. coalesced store to ctx2[h][out_row][i] with the token-rearrange
    {
        const int p  = t >> 5;     // local token 0..7
        const int k4 = t & 31;     // float4 index within 128-col row
        const int b   = bp >> 5;
        const int rem = bp & 31;
        const int d   = rem >> 4;
        const int hh  = (rem >> 2) & 3;
        const int w   = rem & 3;
        const int p1 = p >> 2, p2 = (p >> 1) & 1, p3 = p & 1;
        const int tok = ((((d*2 + p1)*4 + hh)*2 + p2)*4 + w)*2 + p3;
        const int row = b * 256 + tok;
        ((float4*)(ctx2 + ((size_t)h * 4096 + row) * C))[k4] =
            ((const float4*)emb_s)[p * 32 + k4];
    }
}

// ---- Kernel C: out = sum_h ctx2[h] @ Wout_h, Wout_h[i][col] = Wout[i*8+h][col]
__global__ __launch_bounds__(256) void out_gemm2(
    const float* __restrict__ ctx2,  // [8][4096][128]
    const float* __restrict__ Wout,  // (1024, 128)
    float* __restrict__ out)         // (4096, 128)
{
    __shared__ float A_s[8 * 128];   // 4 KB: 8 rows x 128 k
    const int t    = threadIdx.x;
    const int col  = t & 127;
    const int rg   = t >> 7;         // 0/1 -> 4 rows each
    const int row0 = blockIdx.x * 8;

    float acc[4] = {0,0,0,0};
    for (int h = 0; h < 8; ++h) {
        __syncthreads();
        ((float4*)A_s)[t] =
            ((const float4*)(ctx2 + ((size_t)h * 4096 + row0) * 128))[t];
        __syncthreads();
        #pragma unroll
        for (int k4 = 0; k4 < 32; ++k4) {
            const float w0 = Wout[((k4*4 + 0) * 8 + h) * 128 + col];
            const float w1 = Wout[((k4*4 + 1) * 8 + h) * 128 + col];
            const float w2 = Wout[((k4*4 + 2) * 8 + h) * 128 + col];
            const float w3 = Wout[((k4*4 + 3) * 8 + h) * 128 + col];
            #pragma unroll
            for (int r = 0; r < 4; ++r) {
                const float4 cv = ((const float4*)A_s)[(rg*4 + r) * 32 + k4];
                acc[r] = fmaf(cv.x, w0, acc[r]);
                acc[r] = fmaf(cv.y, w1, acc[r]);
                acc[r] = fmaf(cv.z, w2, acc[r]);
                acc[r] = fmaf(cv.w, w3, acc[r]);
            }
        }
    }
    #pragma unroll
    for (int r = 0; r < 4; ++r)
        out[(size_t)(row0 + rg*4 + r) * 128 + col] = acc[r];
}

extern "C" void kernel_launch(void* const* d_in, const int* in_sizes, int n_in,
                              void* d_out, int out_size, void* d_ws, size_t ws_size,
                              hipStream_t stream) {
    const float* emb  = (const float*)d_in[0];
    const float* Wq   = (const float*)d_in[1];
    const float* Wk   = (const float*)d_in[2];
    const float* Wv   = (const float*)d_in[3];
    const float* Wout = (const float*)d_in[4];
    float* out  = (float*)d_out;

    float* ctx2 = (float*)d_ws;                                   // 16 MB
    float* Wp   = (float*)((char*)d_ws + (16u << 20));            // 1.5 MB
    const size_t need = (16u << 20) + 3u * 131072u * sizeof(float);
    const int perm = (ws_size >= need) ? 1 : 0;

    if (perm)
        permute_w_kernel<<<512, 256, 0, stream>>>(Wq, Wk, Wv, Wp);

    attn_fused2<<<4096, 256, 0, stream>>>(
        emb,
        perm ? Wp           : Wq,
        perm ? Wp + 131072  : Wk,
        perm ? Wp + 262144  : Wv,
        perm, ctx2);

    out_gemm2<<<512, 256, 0, stream>>>(ctx2, Wout, out);
}

// Round 3
// 169.711 us; speedup vs baseline: 5.7776x; 1.4924x over previous
//
#include <hip/hip_runtime.h>
#include <hip/hip_bf16.h>
#include <math.h>

// Self_Attention_Local, R3: full bf16-MFMA pipeline.
//   K0: fp32 -> bf16 conversions + weight layout permutes
//   K1: fused QKV + scores(32x32x16, K=8) + instnorm-folded softmax + PV(16x16x32)
//       one block = 4 patches x 1 head; one wave = 1 patch end-to-end for attn
//   K3: out GEMM (4096x1024)@(1024x128) bf16 MFMA
//
// Layout notes (verified mappings from guide):
//   16x16x32 bf16: A[m=lane&15][k=(lane>>4)*8+j], B[k=(lane>>4)*8+j][n=lane&15],
//                  C: col=lane&15, row=(lane>>4)*4+reg
//   32x32x16 bf16: A[m=lane&31][k=(lane>>5)*8+j] (by symmetry), C: col=lane&31,
//                  row=(reg&3)+8*(reg>>2)+4*(lane>>5)

typedef short bfrag  __attribute__((ext_vector_type(8)));   // 8 bf16 in 4 VGPRs
typedef float f32x4  __attribute__((ext_vector_type(4)));
typedef float f32x16 __attribute__((ext_vector_type(16)));

static __device__ __forceinline__ short f2bf(float x) {
    unsigned u = __builtin_bit_cast(unsigned, x);
    u = (u + 0x7fffu + ((u >> 16) & 1u)) >> 16;     // RNE
    return (short)u;
}

// ---- K0: convert emb (4096x128) to bf16; permute W's to bf16 layouts ----
//   Wp[x][h][i][k] = Wx[k][i*8+h]   (x in {q,k,v})
//   Wout_t[col][h*128+i] = Wout[i*8+h][col]
__global__ __launch_bounds__(256) void convert_kernel(
    const float* __restrict__ emb, const float* __restrict__ Wq,
    const float* __restrict__ Wk,  const float* __restrict__ Wv,
    const float* __restrict__ Wout,
    short* __restrict__ emb_bf, short* __restrict__ Wp, short* __restrict__ Wout_t)
{
    const int gid = blockIdx.x * 256 + threadIdx.x;   // 0..524287
    emb_bf[gid] = f2bf(emb[gid]);
    if (gid < 131072) {
        const int k = gid >> 10, c = gid & 1023;
        const int i = c >> 3, h = c & 7;
        const int dst = (h * 128 + i) * 128 + k;
        Wp[dst]          = f2bf(Wq[gid]);
        Wp[131072 + dst] = f2bf(Wk[gid]);
        Wp[262144 + dst] = f2bf(Wv[gid]);
        const int r = gid >> 7, col = gid & 127;
        const int i2 = r >> 3, h2 = r & 7;
        Wout_t[col * 1024 + h2 * 128 + i2] = f2bf(Wout[gid]);
    }
}

// ---- K1: fused attention ----
#define LDP 136   // P-band leading dim (bf16 elems); 272 B rows, 16B-aligned

__global__ __launch_bounds__(256) void attn_mfma(
    const short* __restrict__ emb_bf,  // [4096][128]
    const short* __restrict__ Wp,      // [3][8][128][128]
    short* __restrict__ ctx2)          // [4096 out-rows][h*128+i] bf16
{
    const int bid = blockIdx.x;        // 0..1023
    const int pg  = bid >> 3;          // patch group of 4
    const int h   = bid & 7;
    const int t   = threadIdx.x;
    const int w    = t >> 6;           // wave 0..3
    const int lane = t & 63;

    __shared__ short Qt[4 * 128 * 8];  // [pl][i][p]  8 KB
    __shared__ short Kt[4 * 128 * 8];  // [pl][j][p]  8 KB
    __shared__ short Vs[4 * 8 * 128];  // [pl][p][j]  8 KB
    __shared__ short Ps[4 * 32 * LDP]; // per-wave P band, ~34 KB

    const int m16 = lane & 15;
    const int q8  = (lane >> 4) * 8;

    // ---------------- QKV: (32x128) @ per-head W (128x128) x3, 16x16x32 ----
    {
        bfrag a[2][4];
        #pragma unroll
        for (int tm = 0; tm < 2; ++tm)
            #pragma unroll
            for (int ks = 0; ks < 4; ++ks)
                a[tm][ks] = *(const bfrag*)&emb_bf[(pg*32 + tm*16 + m16)*128 + ks*32 + q8];

        #pragma unroll
        for (int tt = 0; tt < 6; ++tt) {
            const int nt = w * 6 + tt;       // global N-tile 0..23 (q,k,v x 8)
            const int x  = nt >> 3;
            const int i0 = (nt & 7) * 16;
            const short* Wb = Wp + ((x*8 + h)*128 + i0 + m16) * 128;
            bfrag b[4];
            #pragma unroll
            for (int ks = 0; ks < 4; ++ks)
                b[ks] = *(const bfrag*)&Wb[ks*32 + q8];
            f32x4 c0, c1;
            #pragma unroll
            for (int r = 0; r < 4; ++r) { c0[r] = 0.f; c1[r] = 0.f; }
            #pragma unroll
            for (int ks = 0; ks < 4; ++ks) {
                c0 = __builtin_amdgcn_mfma_f32_16x16x32_bf16(a[0][ks], b[ks], c0, 0, 0, 0);
                c1 = __builtin_amdgcn_mfma_f32_16x16x32_bf16(a[1][ks], b[ks], c1, 0, 0, 0);
            }
            #pragma unroll
            for (int tm = 0; tm < 2; ++tm) {
                const f32x4 cc = tm ? c1 : c0;
                const int mrow0 = tm*16 + (lane >> 4)*4;  // 4 consecutive rows
                const int pl = mrow0 >> 3;
                const int p0 = mrow0 & 7;                 // 0 or 4
                const int col = i0 + m16;
                if (x < 2) {            // Q/K transposed: T[pl][col][p]
                    short4 v;
                    v.x = f2bf(cc[0]); v.y = f2bf(cc[1]);
                    v.z = f2bf(cc[2]); v.w = f2bf(cc[3]);
                    short* dst = (x == 0 ? Qt : Kt) + pl*1024 + col*8 + p0;
                    *(short4*)dst = v;
                } else {                // V natural: Vs[pl][p][j]
                    #pragma unroll
                    for (int r = 0; r < 4; ++r)
                        Vs[pl*1024 + (p0 + r)*128 + col] = f2bf(cc[r]);
                }
            }
        }
    }
    __syncthreads();

    // ---------------- attention: wave w owns patch pl = w ----------------
    const int pl  = w;
    const int l31 = lane & 31;
    const int hi  = lane >> 5;

    // score frags (K=8 real, hi-half k=8..15 zeroed)
    bfrag as[4], bs[4];
    #pragma unroll
    for (int mb = 0; mb < 4; ++mb) {
        if (hi == 0) {
            as[mb] = *(const bfrag*)&Qt[pl*1024 + (mb*32 + l31)*8];
            bs[mb] = *(const bfrag*)&Kt[pl*1024 + (mb*32 + l31)*8];
        } else {
            #pragma unroll
            for (int j = 0; j < 8; ++j) { as[mb][j] = 0; bs[mb][j] = 0; }
        }
    }
    // V frags for PV (B: n=p, only p<8 valid)
    bfrag bv[4];
    #pragma unroll
    for (int ks = 0; ks < 4; ++ks) {
        if (m16 < 8)
            bv[ks] = *(const bfrag*)&Vs[pl*1024 + m16*128 + ks*32 + q8];
        else {
            #pragma unroll
            for (int j = 0; j < 8; ++j) bv[ks][j] = 0;
        }
    }

    // pass 1: instance-norm stats over the full 128x128 map (biased var)
    float ls = 0.f, lq = 0.f;
    #pragma unroll
    for (int mb = 0; mb < 4; ++mb)
        #pragma unroll
        for (int nb = 0; nb < 4; ++nb) {
            f32x16 c;
            #pragma unroll
            for (int r = 0; r < 16; ++r) c[r] = 0.f;
            c = __builtin_amdgcn_mfma_f32_32x32x16_bf16(as[mb], bs[nb], c, 0, 0, 0);
            #pragma unroll
            for (int r = 0; r < 16; ++r) { ls += c[r]; lq = fmaf(c[r], c[r], lq); }
        }
    #pragma unroll
    for (int off = 32; off >= 1; off >>= 1) {
        ls += __shfl_xor(ls, off);
        lq += __shfl_xor(lq, off);
    }
    const float mean = ls * (1.f / 16384.f);
    const float var  = lq * (1.f / 16384.f) - mean * mean;
    // mu cancels in softmax: exp((S-max)*rs); fold log2(e) for exp2
    const float rs2  = rsqrtf(var + 1e-5f) * 1.44269504f;

    // out-row mapping for this wave's patch (per lane p = m16)
    const int pat = pg * 4 + pl;
    const int bb  = pat >> 5, rem = pat & 31;
    const int dd  = rem >> 4, hh = (rem >> 2) & 3, ww = rem & 3;
    int row_out = 0;
    if (m16 < 8) {
        const int p1 = m16 >> 2, p2 = (m16 >> 1) & 1, p3 = m16 & 1;
        row_out = bb * 256 + ((((dd*2 + p1)*4 + hh)*2 + p2)*4 + ww)*2 + p3;
    }

    short* Pw = Ps + w * (32 * LDP);

    // pass 2: per 32-row band: recompute scores, softmax, P->LDS, PV
    #pragma unroll 1
    for (int mb = 0; mb < 4; ++mb) {
        f32x16 c[4];
        #pragma unroll
        for (int nb = 0; nb < 4; ++nb) {
            #pragma unroll
            for (int r = 0; r < 16; ++r) c[nb][r] = 0.f;
            c[nb] = __builtin_amdgcn_mfma_f32_32x32x16_bf16(as[mb], bs[nb], c[nb], 0, 0, 0);
        }
        #pragma unroll
        for (int r = 0; r < 16; ++r) {
            float mx = fmaxf(fmaxf(c[0][r], c[1][r]), fmaxf(c[2][r], c[3][r]));
            #pragma unroll
            for (int off = 1; off <= 16; off <<= 1)
                mx = fmaxf(mx, __shfl_xor(mx, off));        // row within 32-lane half
            const float e0 = exp2f((c[0][r] - mx) * rs2);
            const float e1 = exp2f((c[1][r] - mx) * rs2);
            const float e2 = exp2f((c[2][r] - mx) * rs2);
            const float e3 = exp2f((c[3][r] - mx) * rs2);
            float s = (e0 + e1) + (e2 + e3);
            #pragma unroll
            for (int off = 1; off <= 16; off <<= 1)
                s += __shfl_xor(s, off);
            const float iv = 1.0f / s;
            const int rl = (r & 3) + 8 * (r >> 2) + 4 * hi; // local row 0..31
            short* pr = Pw + rl * LDP + l31;
            pr[0]  = f2bf(e0 * iv);
            pr[32] = f2bf(e1 * iv);
            pr[64] = f2bf(e2 * iv);
            pr[96] = f2bf(e3 * iv);
        }
        // PV: (32x128) @ V^T(128x8) via 16x16x32, 2 M-tiles
        #pragma unroll
        for (int tm = 0; tm < 2; ++tm) {
            f32x4 ctx;
            #pragma unroll
            for (int r = 0; r < 4; ++r) ctx[r] = 0.f;
            #pragma unroll
            for (int ks = 0; ks < 4; ++ks) {
                bfrag ap = *(const bfrag*)&Pw[(tm*16 + m16)*LDP + ks*32 + q8];
                ctx = __builtin_amdgcn_mfma_f32_16x16x32_bf16(ap, bv[ks], ctx, 0, 0, 0);
            }
            if (m16 < 8) {
                const int i0g = mb*32 + tm*16 + (lane >> 4)*4;
                short4 v;
                v.x = f2bf(ctx[0]); v.y = f2bf(ctx[1]);
                v.z = f2bf(ctx[2]); v.w = f2bf(ctx[3]);
                *(short4*)&ctx2[(size_t)row_out * 1024 + h * 128 + i0g] = v;
            }
        }
    }
}

// ---- K3: out (4096x128) = ctx2 (4096x1024) @ Wout (1024x128), bf16 MFMA ----
__global__ __launch_bounds__(256) void out_mfma(
    const short* __restrict__ ctx2,    // [4096][1024]
    const short* __restrict__ Wout_t,  // [128][1024]
    float* __restrict__ out)           // [4096][128]
{
    const int t = threadIdx.x;
    const int w = t >> 6, lane = t & 63;
    const int m16 = lane & 15, q8 = (lane >> 4) * 8;
    const int row0 = blockIdx.x * 16;  // 256 blocks

    f32x4 acc0, acc1;
    #pragma unroll
    for (int r = 0; r < 4; ++r) { acc0[r] = 0.f; acc1[r] = 0.f; }
    const short* arow = ctx2   + (size_t)(row0 + m16) * 1024 + q8;
    const short* b0   = Wout_t + (size_t)((w*2 + 0)*16 + m16) * 1024 + q8;
    const short* b1   = Wout_t + (size_t)((w*2 + 1)*16 + m16) * 1024 + q8;
    #pragma unroll 4
    for (int ks = 0; ks < 32; ++ks) {
        const bfrag a   = *(const bfrag*)&arow[ks*32];
        const bfrag vb0 = *(const bfrag*)&b0[ks*32];
        const bfrag vb1 = *(const bfrag*)&b1[ks*32];
        acc0 = __builtin_amdgcn_mfma_f32_16x16x32_bf16(a, vb0, acc0, 0, 0, 0);
        acc1 = __builtin_amdgcn_mfma_f32_16x16x32_bf16(a, vb1, acc1, 0, 0, 0);
    }
    const int r0 = (lane >> 4) * 4;
    #pragma unroll
    for (int r = 0; r < 4; ++r) {
        out[(size_t)(row0 + r0 + r)*128 + (w*2 + 0)*16 + m16] = acc0[r];
        out[(size_t)(row0 + r0 + r)*128 + (w*2 + 1)*16 + m16] = acc1[r];
    }
}

extern "C" void kernel_launch(void* const* d_in, const int* in_sizes, int n_in,
                              void* d_out, int out_size, void* d_ws, size_t ws_size,
                              hipStream_t stream) {
    const float* emb  = (const float*)d_in[0];   // (512, 8, 128)
    const float* Wq   = (const float*)d_in[1];   // (128, 1024)
    const float* Wk   = (const float*)d_in[2];
    const float* Wv   = (const float*)d_in[3];
    const float* Wout = (const float*)d_in[4];   // (1024, 128)
    float* out = (float*)d_out;

    // ws layout (shorts): ctx2 4M | emb_bf 512K | Wp 384K | Wout_t 128K = 10 MB
    short* ctx2   = (short*)d_ws;
    short* emb_bf = ctx2 + 4194304;
    short* Wp     = emb_bf + 524288;
    short* Wout_t = Wp + 393216;

    convert_kernel<<<2048, 256, 0, stream>>>(emb, Wq, Wk, Wv, Wout,
                                             emb_bf, Wp, Wout_t);
    attn_mfma<<<1024, 256, 0, stream>>>(emb_bf, Wp, ctx2);
    out_mfma<<<256, 256, 0, stream>>>(ctx2, Wout_t, out);
}